// Round 3
// baseline (650.021 us; speedup 1.0000x reference)
//
#include <hip/hip_runtime.h>
#include <cstdint>

// B=8, Cin=Cout=128, x 128x128 -> out 256x256.
#define SCALE_MAIN 0.029462782549439483f   // 1/sqrt(128*9)
#define LSCALE     0.044194173824159223f   // 1/sqrt(512)
#define CSCALE     0.029462782549439483f   // 1/sqrt(128*9)

typedef __attribute__((ext_vector_type(8))) short bf16x8;
typedef __attribute__((ext_vector_type(4))) float f32x4;
typedef __attribute__((ext_vector_type(4))) unsigned int u32x4;

static __device__ __forceinline__ float lrelu_s2(float v) {
  return (v > 0.f ? v : 0.2f * v) * 1.4142135623730951f;
}

static __device__ __forceinline__ unsigned short f2bf(float f) {
  unsigned int u = __builtin_bit_cast(unsigned int, f);
  u += 0x7FFFu + ((u >> 16) & 1u);
  return (unsigned short)(u >> 16);
}

// K0: effective fused convT+blur kernel, bf16 in MFMA-B layout:
// kb[par][k/8][co][j], k = tap*128 + ci (tap = a*3+b2), j = ci&7.
__global__ __launch_bounds__(256) void keffb_kernel(const float* __restrict__ weight,
                                                    short* __restrict__ kb) {
  int idx = blockIdx.x * 256 + threadIdx.x;
  if (idx >= 128 * 128 * 36) return;
  int tap = idx % 9;
  int tmp = idx / 9;
  int par = tmp & 3;
  int cc  = tmp >> 2;            // co*128 + ci
  int co = cc >> 7, ci = cc & 127;
  int ph = par >> 1, pw = par & 1;
  int a = tap / 3, b = tap % 3;
  int th = ph ? 3 - 2 * a : 2 - 2 * a;
  int tw = pw ? 3 - 2 * b : 2 - 2 * b;
  const float k4[4] = {1.f, 3.f, 3.f, 1.f};
  const float* wp = weight + cc * 9;
  float acc = 0.f;
  #pragma unroll
  for (int u = 0; u < 4; ++u) {
    int m = th - 1 + u;
    if (m < 0 || m > 2) continue;
    #pragma unroll
    for (int v = 0; v < 4; ++v) {
      int n = tw - 1 + v;
      if (n < 0 || n > 2) continue;
      acc += (k4[3 - u] * k4[3 - v] * (1.f / 16.f)) * wp[m * 3 + n];
    }
  }
  kb[(((par * 144) + tap * 16 + (ci >> 3)) * 128 + co) * 8 + (ci & 7)] =
      (short)f2bf(acc * SCALE_MAIN);
}

// K_t: x NCHW fp32 -> NHWC bf16 via LDS-tiled transpose. Block = (y, b).
__global__ __launch_bounds__(256) void xpose_kernel(const float* __restrict__ x,
                                                    unsigned short* __restrict__ xt) {
  int y = blockIdx.x, b = blockIdx.y;
  __shared__ unsigned short tl[128 * 134];
  int t = threadIdx.x;
  #pragma unroll 4
  for (int i = 0; i < 16; ++i) {
    int c = t + i * 256;
    int ci = c >> 5, x4 = c & 31;
    f32x4 v = *(const f32x4*)(x + (size_t)(b * 128 + ci) * 16384 + y * 128 + x4 * 4);
    unsigned int* dst = (unsigned int*)(tl + ci * 134 + x4 * 4);
    dst[0] = (unsigned int)f2bf(v.x) | ((unsigned int)f2bf(v.y) << 16);
    dst[1] = (unsigned int)f2bf(v.z) | ((unsigned int)f2bf(v.w) << 16);
  }
  __syncthreads();
  #pragma unroll 2
  for (int i = 0; i < 8; ++i) {
    int c = t + i * 256;
    int xcol = c >> 4, sub = c & 15;
    unsigned short u[8];
    #pragma unroll
    for (int j = 0; j < 8; ++j) u[j] = tl[(sub * 8 + j) * 134 + xcol];
    u32x4 o;
    o.x = (unsigned int)u[0] | ((unsigned int)u[1] << 16);
    o.y = (unsigned int)u[2] | ((unsigned int)u[3] << 16);
    o.z = (unsigned int)u[4] | ((unsigned int)u[5] << 16);
    o.w = (unsigned int)u[6] | ((unsigned int)u[7] << 16);
    *(u32x4*)(xt + ((size_t)(b * 128 + y) * 128 + xcol) * 128 + sub * 8) = o;
  }
}

// K1: style GEMV + fused lrelu -> smap[b][32768]
__global__ __launch_bounds__(256) void style_kernel(const float* __restrict__ style,
                                                    const float* __restrict__ lin_w,
                                                    const float* __restrict__ lin_b,
                                                    float* __restrict__ smap) {
  int wid = threadIdx.x >> 6, lane = threadIdx.x & 63;
  int gw = blockIdx.x * 4 + wid;
  const float4* st4 = (const float4*)style;
  float s[8][8];
  #pragma unroll
  for (int b = 0; b < 8; ++b) {
    float4 a0 = st4[b * 128 + lane * 2];
    float4 a1 = st4[b * 128 + lane * 2 + 1];
    s[b][0] = a0.x; s[b][1] = a0.y; s[b][2] = a0.z; s[b][3] = a0.w;
    s[b][4] = a1.x; s[b][5] = a1.y; s[b][6] = a1.z; s[b][7] = a1.w;
  }
  for (int rr = 0; rr < 16; ++rr) {
    int j = gw * 16 + rr;
    const float4* wp = (const float4*)(lin_w + (size_t)j * 512);
    float4 w0 = wp[lane * 2], w1 = wp[lane * 2 + 1];
    float acc[8];
    #pragma unroll
    for (int b = 0; b < 8; ++b) {
      acc[b] = w0.x * s[b][0] + w0.y * s[b][1] + w0.z * s[b][2] + w0.w * s[b][3]
             + w1.x * s[b][4] + w1.y * s[b][5] + w1.z * s[b][6] + w1.w * s[b][7];
    }
    #pragma unroll
    for (int m = 32; m; m >>= 1) {
      #pragma unroll
      for (int b = 0; b < 8; ++b) acc[b] += __shfl_xor(acc[b], m, 64);
    }
    if (lane == 0) {
      float bias = lin_b[j];
      #pragma unroll
      for (int b = 0; b < 8; ++b)
        smap[(size_t)b * 32768 + j] = lrelu_s2(acc[b] * LSCALE + bias);
    }
  }
}

// K2: the two 3x3 modulation convs on the 32x32 upsampled style map.
__global__ __launch_bounds__(256) void modconv_kernel(const float* __restrict__ smap,
    const float* __restrict__ cw_w, const float* __restrict__ cw_b,
    const float* __restrict__ cb_w, const float* __restrict__ cb_b,
    float* __restrict__ sw, float* __restrict__ sb) {
  int co = blockIdx.x, b = blockIdx.y;
  int t = threadIdx.x;
  __shared__ float sm[256];
  int h0 = 2 * (t >> 4), w0 = 2 * (t & 15);
  float aw[4] = {0, 0, 0, 0}, ab[4] = {0, 0, 0, 0};
  for (int ci = 0; ci < 128; ++ci) {
    __syncthreads();
    sm[t] = smap[((size_t)b * 128 + ci) * 256 + t];
    __syncthreads();
    const float* wwp = cw_w + (co * 128 + ci) * 9;
    const float* wbp = cb_w + (co * 128 + ci) * 9;
    #pragma unroll
    for (int kh = 0; kh < 3; ++kh)
    #pragma unroll
    for (int kw = 0; kw < 3; ++kw) {
      float wwv = wwp[kh * 3 + kw], wbv = wbp[kh * 3 + kw];
      #pragma unroll
      for (int q = 0; q < 4; ++q) {
        int h = h0 + (q >> 1), w = w0 + (q & 1);
        int y = h - 1 + kh, xx = w - 1 + kw;
        float v = (y >= 0 && y < 32 && xx >= 0 && xx < 32) ? sm[(y >> 1) * 16 + (xx >> 1)] : 0.f;
        aw[q] += wwv * v;
        ab[q] += wbv * v;
      }
    }
  }
  float bw = cw_b[co], bb = cb_b[co];
  #pragma unroll
  for (int q = 0; q < 4; ++q) {
    int h = h0 + (q >> 1), w = w0 + (q & 1);
    size_t o = ((size_t)(b * 128 + co) * 32 + h) * 32 + w;
    sw[o] = aw[q] * CSCALE + bw;
    sb[o] = ab[q] * CSCALE + bb;
  }
}

// K3: MFMA implicit-GEMM fused convT+blur.
// Block: 64-pixel row strip (b, y0, xh). 4 waves, one per parity p.
// Wave: mf=4 (64 pixels) x nf=8 (all 128 co), acc 4x8 f32x4 (AGPR).
// A-tile in LDS with chunk swizzle phys=(c&8)|((c+2S)&7) -> read bank-group
// (c+3S)%8: conflict-free ds_read_b128. K-loop barrier-free.
template <int BF16OUT>
__global__ __launch_bounds__(256) void main_kernel(const unsigned short* __restrict__ xt,
    const short* __restrict__ kb, float* __restrict__ out,
    unsigned short* __restrict__ xout, float* __restrict__ partial) {
  __shared__ __align__(16) char smem[53856];   // A-tile 198*272; reused for eps
  int xh = blockIdx.x, y0 = blockIdx.y, b = blockIdx.z;
  int x0 = xh * 64;
  int t = threadIdx.x;
  int lane = t & 63, p = t >> 6;               // p = parity 0..3
  int m15 = lane & 15, ksub = lane >> 4;

  // ---- stage A tile: 198 spatial x 128 ci bf16, swizzled chunks ----
  const char* xtc = (const char*)xt;
  for (int c = t; c < 3168; c += 256) {
    int spos = c >> 4, sub = c & 15;
    int aa = spos / 66, cc2 = spos - aa * 66;
    int y = y0 - 1 + aa, xg = x0 - 1 + cc2;
    f32x4 v = {0.f, 0.f, 0.f, 0.f};
    if ((unsigned)y < 128u && (unsigned)xg < 128u)
      v = *(const f32x4*)(xtc + ((size_t)((b * 128 + y) * 128 + xg)) * 256 + sub * 16);
    int phys = (sub & 8) | ((sub + 2 * spos) & 7);
    *(f32x4*)(smem + spos * 272 + phys * 16) = v;
  }
  __syncthreads();

  // ---- K loop: 36 steps (9 taps x 4 ci-chunks of 32) ----
  const bf16x8* kbv = (const bf16x8*)kb;
  int bbase = p * 18432 + ksub * 128 + m15;

  f32x4 acc[4][8];
  #pragma unroll
  for (int i = 0; i < 4; ++i)
  #pragma unroll
  for (int j = 0; j < 8; ++j) acc[i][j] = (f32x4){0.f, 0.f, 0.f, 0.f};

  for (int s = 0; s < 36; ++s) {
    int tap = s >> 2;
    int ta = tap / 3, tb = tap - ta * 3;
    int sp = ta * 66 + tb;
    int S = m15 + sp;
    int c = ((s & 3) << 2) + ksub;
    int phys = (c & 8) | ((c + 2 * S) & 7);
    const char* ab = smem + S * 272 + phys * 16;
    bf16x8 av[4];
    #pragma unroll
    for (int mf = 0; mf < 4; ++mf) av[mf] = *(const bf16x8*)(ab + mf * 4352);
    #pragma unroll
    for (int nf = 0; nf < 8; ++nf) {
      bf16x8 bv = kbv[bbase + s * 512 + nf * 16];
      #pragma unroll
      for (int mf = 0; mf < 4; ++mf)
        acc[mf][nf] = __builtin_amdgcn_mfma_f32_16x16x32_bf16(av[mf], bv, acc[mf][nf], 0, 0, 0);
    }
  }

  __syncthreads();                   // all waves done with A-tile before eps reuse
  // ---- epilogue: per nf: eps dump + stats + coalesced write ----
  float* eps = (float*)smem;         // [par 4][xx 64][slot 19 (16 used)]
  #pragma unroll
  for (int nf = 0; nf < 8; ++nf) {
    float s1 = 0.f, s2 = 0.f;
    #pragma unroll
    for (int mf = 0; mf < 4; ++mf) {
      #pragma unroll
      for (int r = 0; r < 4; ++r) {
        int xx = mf * 16 + ksub * 4 + r;
        float v = acc[mf][nf][r];
        eps[(p * 64 + xx) * 19 + m15] = v;
        s1 += v; s2 += v * v;
      }
    }
    s1 += __shfl_xor(s1, 16, 64); s1 += __shfl_xor(s1, 32, 64);
    s2 += __shfl_xor(s2, 16, 64); s2 += __shfl_xor(s2, 32, 64);
    if (lane < 16) {
      int co = nf * 16 + lane;
      size_t pidx = (((((size_t)b * 128 + co) * 128 + y0) * 2 + xh) * 4 + p) * 2;
      partial[pidx] = s1; partial[pidx + 1] = s2;
    }
    __syncthreads();
    int r2 = t >> 3;
    int col = r2 & 15, ph2 = r2 >> 4;
    int co = nf * 16 + col;
    int w0 = (t & 7) * 16;
    int h = 2 * y0 + ph2;
    float vv[16];
    #pragma unroll
    for (int i = 0; i < 16; ++i) {
      int wl = w0 + i;
      vv[i] = eps[(((ph2 * 2 + (wl & 1)) * 64) + (wl >> 1)) * 19 + col];
    }
    size_t obase = ((size_t)(b * 128 + co) * 256 + h) * 256 + xh * 128 + w0;
    if (BF16OUT) {
      u32x4 o0, o1;
      o0.x = (unsigned int)f2bf(vv[0])  | ((unsigned int)f2bf(vv[1])  << 16);
      o0.y = (unsigned int)f2bf(vv[2])  | ((unsigned int)f2bf(vv[3])  << 16);
      o0.z = (unsigned int)f2bf(vv[4])  | ((unsigned int)f2bf(vv[5])  << 16);
      o0.w = (unsigned int)f2bf(vv[6])  | ((unsigned int)f2bf(vv[7])  << 16);
      o1.x = (unsigned int)f2bf(vv[8])  | ((unsigned int)f2bf(vv[9])  << 16);
      o1.y = (unsigned int)f2bf(vv[10]) | ((unsigned int)f2bf(vv[11]) << 16);
      o1.z = (unsigned int)f2bf(vv[12]) | ((unsigned int)f2bf(vv[13]) << 16);
      o1.w = (unsigned int)f2bf(vv[14]) | ((unsigned int)f2bf(vv[15]) << 16);
      *(u32x4*)(xout + obase) = o0;
      *(u32x4*)(xout + obase + 8) = o1;
    } else {
      #pragma unroll
      for (int i = 0; i < 4; ++i) {
        f32x4 o4 = {vv[i * 4], vv[i * 4 + 1], vv[i * 4 + 2], vv[i * 4 + 3]};
        *(f32x4*)(out + obase + i * 4) = o4;
      }
    }
    __syncthreads();
  }
}

// K4: reduce 2048 partials per (b,c) -> mean, rstd.
__global__ __launch_bounds__(256) void stats_kernel(const float* __restrict__ partial,
                                                    float* __restrict__ stats) {
  int bc = blockIdx.x;
  int t = threadIdx.x;
  float s1 = 0.f, s2 = 0.f;
  for (int j = t; j < 1024; j += 256) {
    s1 += partial[(size_t)bc * 2048 + 2 * j];
    s2 += partial[(size_t)bc * 2048 + 2 * j + 1];
  }
  #pragma unroll
  for (int m = 32; m; m >>= 1) { s1 += __shfl_xor(s1, m, 64); s2 += __shfl_xor(s2, m, 64); }
  __shared__ float rb[8];
  if ((t & 63) == 0) { rb[(t >> 6) * 2] = s1; rb[(t >> 6) * 2 + 1] = s2; }
  __syncthreads();
  if (t == 0) {
    float a1 = rb[0] + rb[2] + rb[4] + rb[6];
    float a2 = rb[1] + rb[3] + rb[5] + rb[7];
    float mean = a1 * (1.f / 65536.f);
    float var = a2 * (1.f / 65536.f) - mean * mean;
    stats[bc * 2] = mean;
    stats[bc * 2 + 1] = rsqrtf(var + 1e-5f);
  }
}

// K5a: normalize + modulate, fp32 in-place path.
__global__ __launch_bounds__(256) void final_kernel(float* __restrict__ out,
    const float* __restrict__ sw, const float* __restrict__ sb,
    const float* __restrict__ stats) {
  unsigned int tid = blockIdx.x * 256 + threadIdx.x;
  unsigned int e = tid * 4;
  unsigned int w = e & 255u;
  unsigned int h = (e >> 8) & 255u;
  unsigned int bc = e >> 16;
  float mean = stats[bc * 2], rstd = stats[bc * 2 + 1];
  unsigned int sidx = (bc * 32 + (h >> 3)) * 32 + (w >> 3);
  float f1 = (1.f + 0.3f * sw[sidx]) * rstd;
  float f0 = 0.3f * sb[sidx] - mean * f1;
  float4 v = *(float4*)(out + e);
  v.x = v.x * f1 + f0;
  v.y = v.y * f1 + f0;
  v.z = v.z * f1 + f0;
  v.w = v.w * f1 + f0;
  *(float4*)(out + e) = v;
}

// K5b: normalize + modulate, reading bf16 intermediate, writing fp32 out.
__global__ __launch_bounds__(256) void final_bf16_kernel(float* __restrict__ out,
    const unsigned short* __restrict__ xout,
    const float* __restrict__ sw, const float* __restrict__ sb,
    const float* __restrict__ stats) {
  unsigned int tid = blockIdx.x * 256 + threadIdx.x;
  unsigned int e = tid * 8;
  unsigned int w = e & 255u;
  unsigned int h = (e >> 8) & 255u;
  unsigned int bc = e >> 16;
  float mean = stats[bc * 2], rstd = stats[bc * 2 + 1];
  unsigned int sidx = (bc * 32 + (h >> 3)) * 32 + (w >> 3);
  float f1 = (1.f + 0.3f * sw[sidx]) * rstd;
  float f0 = 0.3f * sb[sidx] - mean * f1;
  u32x4 uv = *(const u32x4*)(xout + e);
  float o[8];
  #pragma unroll
  for (int j = 0; j < 4; ++j) {
    unsigned int word = uv[j];
    float lo = __builtin_bit_cast(float, word << 16);
    float hi = __builtin_bit_cast(float, word & 0xFFFF0000u);
    o[2 * j]     = lo * f1 + f0;
    o[2 * j + 1] = hi * f1 + f0;
  }
  f32x4 a = {o[0], o[1], o[2], o[3]}, c = {o[4], o[5], o[6], o[7]};
  *(f32x4*)(out + e) = a;
  *(f32x4*)(out + e + 4) = c;
}

extern "C" void kernel_launch(void* const* d_in, const int* in_sizes, int n_in,
                              void* d_out, int out_size, void* d_ws, size_t ws_size,
                              hipStream_t stream) {
  const float* x      = (const float*)d_in[0];
  const float* style  = (const float*)d_in[1];
  const float* weight = (const float*)d_in[2];
  const float* lin_w  = (const float*)d_in[3];
  const float* lin_b  = (const float*)d_in[4];
  const float* cw_w   = (const float*)d_in[5];
  const float* cw_b   = (const float*)d_in[6];
  const float* cb_w   = (const float*)d_in[7];
  const float* cb_b   = (const float*)d_in[8];
  float* out = (float*)d_out;
  char* ws = (char*)d_ws;

  short*          kbb   = (short*)(ws);                       // 1,179,648 B
  unsigned short* xt    = (unsigned short*)(ws + 1179648);    // 33,554,432 B
  float*          smap  = (float*)(ws + 34734080);            // 1 MB
  float*          swb   = (float*)(ws + 35782656);            // 4 MB
  float*          sbb   = (float*)(ws + 39976960);            // 4 MB
  float*          part  = (float*)(ws + 44171264);            // 8 MB
  float*          stats = (float*)(ws + 52559872);            // 8 KB
  unsigned short* xout  = (unsigned short*)(ws + 52568064);   // 128 MB (optional)
  bool bigws = ws_size >= (size_t)186785792;

  keffb_kernel<<<dim3(2304), dim3(256), 0, stream>>>(weight, kbb);
  xpose_kernel<<<dim3(128, 8), dim3(256), 0, stream>>>(x, xt);
  style_kernel<<<dim3(512), dim3(256), 0, stream>>>(style, lin_w, lin_b, smap);
  modconv_kernel<<<dim3(128, 8), dim3(256), 0, stream>>>(smap, cw_w, cw_b, cb_w, cb_b, swb, sbb);
  if (bigws) {
    main_kernel<1><<<dim3(2, 128, 8), dim3(256), 0, stream>>>(xt, kbb, out, xout, part);
    stats_kernel<<<dim3(1024), dim3(256), 0, stream>>>(part, stats);
    final_bf16_kernel<<<dim3(32768), dim3(256), 0, stream>>>(out, xout, swb, sbb, stats);
  } else {
    main_kernel<0><<<dim3(2, 128, 8), dim3(256), 0, stream>>>(xt, kbb, out, nullptr, part);
    stats_kernel<<<dim3(1024), dim3(256), 0, stream>>>(part, stats);
    final_kernel<<<dim3(65536), dim3(256), 0, stream>>>(out, swb, sbb, stats);
  }
}

// Round 4
// 393.713 us; speedup vs baseline: 1.6510x; 1.6510x over previous
//
#include <hip/hip_runtime.h>
#include <cstdint>

// B=8, Cin=Cout=128, x 128x128 -> out 256x256.
#define SCALE_MAIN 0.029462782549439483f   // 1/sqrt(128*9)
#define LSCALE     0.044194173824159223f   // 1/sqrt(512)
#define CSCALE     0.029462782549439483f   // 1/sqrt(128*9)

typedef __attribute__((ext_vector_type(8))) short bf16x8;
typedef __attribute__((ext_vector_type(4))) float f32x4;
typedef __attribute__((ext_vector_type(4))) unsigned int u32x4;

static __device__ __forceinline__ float lrelu_s2(float v) {
  return (v > 0.f ? v : 0.2f * v) * 1.4142135623730951f;
}

static __device__ __forceinline__ unsigned short f2bf(float f) {
  unsigned int u = __builtin_bit_cast(unsigned int, f);
  u += 0x7FFFu + ((u >> 16) & 1u);
  return (unsigned short)(u >> 16);
}

// K0: effective fused convT+blur kernel, bf16 in MFMA-B layout:
// kb[par][k/8][co][j], k = tap*128 + ci (tap = a*3+b2), j = ci&7.
__global__ __launch_bounds__(256) void keffb_kernel(const float* __restrict__ weight,
                                                    short* __restrict__ kb) {
  int idx = blockIdx.x * 256 + threadIdx.x;
  if (idx >= 128 * 128 * 36) return;
  int tap = idx % 9;
  int tmp = idx / 9;
  int par = tmp & 3;
  int cc  = tmp >> 2;            // co*128 + ci
  int co = cc >> 7, ci = cc & 127;
  int ph = par >> 1, pw = par & 1;
  int a = tap / 3, b = tap % 3;
  int th = ph ? 3 - 2 * a : 2 - 2 * a;
  int tw = pw ? 3 - 2 * b : 2 - 2 * b;
  const float k4[4] = {1.f, 3.f, 3.f, 1.f};
  const float* wp = weight + cc * 9;
  float acc = 0.f;
  #pragma unroll
  for (int u = 0; u < 4; ++u) {
    int m = th - 1 + u;
    if (m < 0 || m > 2) continue;
    #pragma unroll
    for (int v = 0; v < 4; ++v) {
      int n = tw - 1 + v;
      if (n < 0 || n > 2) continue;
      acc += (k4[3 - u] * k4[3 - v] * (1.f / 16.f)) * wp[m * 3 + n];
    }
  }
  kb[(((par * 144) + tap * 16 + (ci >> 3)) * 128 + co) * 8 + (ci & 7)] =
      (short)f2bf(acc * SCALE_MAIN);
}

// K_t: x NCHW fp32 -> NHWC bf16 via LDS-tiled transpose. Block = (y, b).
__global__ __launch_bounds__(256) void xpose_kernel(const float* __restrict__ x,
                                                    unsigned short* __restrict__ xt) {
  int y = blockIdx.x, b = blockIdx.y;
  __shared__ unsigned short tl[128 * 134];
  int t = threadIdx.x;
  #pragma unroll 4
  for (int i = 0; i < 16; ++i) {
    int c = t + i * 256;
    int ci = c >> 5, x4 = c & 31;
    f32x4 v = *(const f32x4*)(x + (size_t)(b * 128 + ci) * 16384 + y * 128 + x4 * 4);
    unsigned int* dst = (unsigned int*)(tl + ci * 134 + x4 * 4);
    dst[0] = (unsigned int)f2bf(v.x) | ((unsigned int)f2bf(v.y) << 16);
    dst[1] = (unsigned int)f2bf(v.z) | ((unsigned int)f2bf(v.w) << 16);
  }
  __syncthreads();
  #pragma unroll 2
  for (int i = 0; i < 8; ++i) {
    int c = t + i * 256;
    int xcol = c >> 4, sub = c & 15;
    unsigned short u[8];
    #pragma unroll
    for (int j = 0; j < 8; ++j) u[j] = tl[(sub * 8 + j) * 134 + xcol];
    u32x4 o;
    o.x = (unsigned int)u[0] | ((unsigned int)u[1] << 16);
    o.y = (unsigned int)u[2] | ((unsigned int)u[3] << 16);
    o.z = (unsigned int)u[4] | ((unsigned int)u[5] << 16);
    o.w = (unsigned int)u[6] | ((unsigned int)u[7] << 16);
    *(u32x4*)(xt + ((size_t)(b * 128 + y) * 128 + xcol) * 128 + sub * 8) = o;
  }
}

// K1: style GEMV + fused lrelu -> smap[b][32768]
__global__ __launch_bounds__(256) void style_kernel(const float* __restrict__ style,
                                                    const float* __restrict__ lin_w,
                                                    const float* __restrict__ lin_b,
                                                    float* __restrict__ smap) {
  int wid = threadIdx.x >> 6, lane = threadIdx.x & 63;
  int gw = blockIdx.x * 4 + wid;
  const float4* st4 = (const float4*)style;
  float s[8][8];
  #pragma unroll
  for (int b = 0; b < 8; ++b) {
    float4 a0 = st4[b * 128 + lane * 2];
    float4 a1 = st4[b * 128 + lane * 2 + 1];
    s[b][0] = a0.x; s[b][1] = a0.y; s[b][2] = a0.z; s[b][3] = a0.w;
    s[b][4] = a1.x; s[b][5] = a1.y; s[b][6] = a1.z; s[b][7] = a1.w;
  }
  for (int rr = 0; rr < 16; ++rr) {
    int j = gw * 16 + rr;
    const float4* wp = (const float4*)(lin_w + (size_t)j * 512);
    float4 w0 = wp[lane * 2], w1 = wp[lane * 2 + 1];
    float acc[8];
    #pragma unroll
    for (int b = 0; b < 8; ++b) {
      acc[b] = w0.x * s[b][0] + w0.y * s[b][1] + w0.z * s[b][2] + w0.w * s[b][3]
             + w1.x * s[b][4] + w1.y * s[b][5] + w1.z * s[b][6] + w1.w * s[b][7];
    }
    #pragma unroll
    for (int m = 32; m; m >>= 1) {
      #pragma unroll
      for (int b = 0; b < 8; ++b) acc[b] += __shfl_xor(acc[b], m, 64);
    }
    if (lane == 0) {
      float bias = lin_b[j];
      #pragma unroll
      for (int b = 0; b < 8; ++b)
        smap[(size_t)b * 32768 + j] = lrelu_s2(acc[b] * LSCALE + bias);
    }
  }
}

// K2: two 3x3 modulation convs on the upsampled style map.
// Weights (2x1152) + 32-ci smap chunks staged in LDS; per-ci 3x3 register
// patch (the upsampled 3x3 window only touches a 3x3 sm neighborhood).
__global__ __launch_bounds__(256) void modconv_kernel(const float* __restrict__ smap,
    const float* __restrict__ cw_w, const float* __restrict__ cw_b,
    const float* __restrict__ cb_w, const float* __restrict__ cb_b,
    float* __restrict__ sw, float* __restrict__ sb) {
  int co = blockIdx.x, b = blockIdx.y;
  int t = threadIdx.x;
  __shared__ float wts[2][1152];
  __shared__ float smc[8192];
  for (int i = t; i < 1152; i += 256) {
    wts[0][i] = cw_w[(size_t)co * 1152 + i];
    wts[1][i] = cb_w[(size_t)co * 1152 + i];
  }
  int qh = t >> 4, qw = t & 15;          // output quad at (2qh, 2qw)
  float aw[4] = {0, 0, 0, 0}, ab2[4] = {0, 0, 0, 0};
  for (int cc = 0; cc < 4; ++cc) {
    __syncthreads();
    const f32x4* sp4 = (const f32x4*)(smap + (size_t)b * 32768 + cc * 8192);
    f32x4* smc4 = (f32x4*)smc;
    #pragma unroll
    for (int i = 0; i < 8; ++i) smc4[t + i * 256] = sp4[t + i * 256];
    __syncthreads();
    for (int ci = 0; ci < 32; ++ci) {
      const float* sm = smc + ci * 256;
      float pt[3][3];
      #pragma unroll
      for (int dy = 0; dy < 3; ++dy)
      #pragma unroll
      for (int dx = 0; dx < 3; ++dx) {
        int yy = qh - 1 + dy, xx = qw - 1 + dx;
        pt[dy][dx] = (yy >= 0 && yy < 16 && xx >= 0 && xx < 16) ? sm[yy * 16 + xx] : 0.f;
      }
      const float* w0p = &wts[0][(cc * 32 + ci) * 9];
      const float* w1p = &wts[1][(cc * 32 + ci) * 9];
      #pragma unroll
      for (int kh = 0; kh < 3; ++kh)
      #pragma unroll
      for (int kw = 0; kw < 3; ++kw) {
        float wwv = w0p[kh * 3 + kw], wbv = w1p[kh * 3 + kw];
        #pragma unroll
        for (int q = 0; q < 4; ++q) {
          int ey = (q >> 1) - 1 + kh;    // in {-1..2}
          int ex = (q & 1) - 1 + kw;
          int py = (ey < 0) ? 0 : (ey < 2 ? 1 : 2);   // compile-time per (q,kh)
          int px = (ex < 0) ? 0 : (ex < 2 ? 1 : 2);
          float v = pt[py][px];
          aw[q] += wwv * v;
          ab2[q] += wbv * v;
        }
      }
    }
  }
  float bw = cw_b[co], bb = cb_b[co];
  #pragma unroll
  for (int q = 0; q < 4; ++q) {
    int h = 2 * qh + (q >> 1), w = 2 * qw + (q & 1);
    size_t o = ((size_t)(b * 128 + co) * 32 + h) * 32 + w;
    sw[o] = aw[q] * CSCALE + bw;
    sb[o] = ab2[q] * CSCALE + bb;
  }
}

// K3: MFMA implicit-GEMM fused convT+blur.
// Block: 64-pixel row strip (b, y0, xh); 4 waves = 4 parities.
// Wave: mf=4 (64 px) x nf=8 (128 co); acc = 128 AGPR; VGPR capped by
// __launch_bounds__(256,2) -> 2 waves/SIMD, 2 blocks/CU.
// A/B hand-pipelined one K-step ahead (ping-pong regs); K-loop barrier-free.
#define LOADSTEP(S, AV, BV)                                                      \
  {                                                                              \
    int tap_ = (S) >> 2;                                                         \
    int ta_ = (tap_ * 11) >> 5, tb_ = tap_ - ta_ * 3;                            \
    const char* ab_ = abase + (ta_ * 66 + tb_) * 272 + ((S) & 3) * 64;           \
    _Pragma("unroll")                                                            \
    for (int mf = 0; mf < 4; ++mf) AV[mf] = *(const bf16x8*)(ab_ + mf * 4352);   \
    _Pragma("unroll")                                                            \
    for (int nf = 0; nf < 8; ++nf) BV[nf] = kbv[bbase + (S) * 512 + nf * 16];    \
  }
#define MFMASTEP(AV, BV)                                                         \
  _Pragma("unroll")                                                              \
  for (int nf = 0; nf < 8; ++nf)                                                 \
  _Pragma("unroll")                                                              \
  for (int mf = 0; mf < 4; ++mf)                                                 \
    acc[mf][nf] = __builtin_amdgcn_mfma_f32_16x16x32_bf16(AV[mf], BV[nf], acc[mf][nf], 0, 0, 0);

template <int BF16OUT>
__global__ __launch_bounds__(256, 2) void main_kernel(const unsigned short* __restrict__ xt,
    const short* __restrict__ kb, float* __restrict__ out,
    unsigned short* __restrict__ xout, float* __restrict__ partial) {
  __shared__ __align__(16) char smem[53856];   // A-tile 198*272; reused as eps
  int xh = blockIdx.x, y0 = blockIdx.y, b = blockIdx.z;
  int x0 = xh * 64;
  int t = threadIdx.x;
  int lane = t & 63, p = t >> 6;               // p = parity 0..3
  int m15 = lane & 15, ksub = lane >> 4;
  int ph = p >> 1, pw = p & 1;

  // ---- stage A tile: 198 spatial x 128 ci bf16 ----
  const char* xtc = (const char*)xt;
  for (int c = t; c < 3168; c += 256) {
    int spos = c >> 4, sub = c & 15;
    int aa = spos / 66, cc2 = spos - aa * 66;
    int y = y0 - 1 + aa, xg = x0 - 1 + cc2;
    f32x4 v = {0.f, 0.f, 0.f, 0.f};
    if ((unsigned)y < 128u && (unsigned)xg < 128u)
      v = *(const f32x4*)(xtc + ((size_t)((b * 128 + y) * 128 + xg)) * 256 + sub * 16);
    *(f32x4*)(smem + spos * 272 + sub * 16) = v;
  }
  __syncthreads();

  // ---- K loop: 36 steps (9 taps x 4 ci-chunks of 32), pipelined ----
  const bf16x8* kbv = (const bf16x8*)kb;
  int bbase = p * 18432 + ksub * 128 + m15;
  const char* abase = smem + m15 * 272 + ksub * 16;

  f32x4 acc[4][8];
  #pragma unroll
  for (int i = 0; i < 4; ++i)
  #pragma unroll
  for (int j = 0; j < 8; ++j) acc[i][j] = (f32x4){0.f, 0.f, 0.f, 0.f};

  bf16x8 avA[4], bvA[8], avB[4], bvB[8];
  LOADSTEP(0, avA, bvA)
  for (int s = 0; s < 36; s += 2) {
    LOADSTEP(s + 1, avB, bvB)
    MFMASTEP(avA, bvA)
    if (s + 2 < 36) LOADSTEP(s + 2, avA, bvA)
    MFMASTEP(avB, bvB)
  }

  __syncthreads();                   // all waves done with A-tile
  // ---- epilogue: 4 rounds of 2 nf; eps [e2][ph2][w128][17] ----
  float* eps = (float*)smem;
  int co16 = t & 15, slotid = t >> 4;
  int ph2 = slotid >> 3, w16 = slotid & 7;
  #pragma unroll
  for (int r2 = 0; r2 < 4; ++r2) {
    #pragma unroll
    for (int e = 0; e < 2; ++e) {
      int nf = r2 * 2 + e;
      float s1 = 0.f, s2 = 0.f;
      #pragma unroll
      for (int mf = 0; mf < 4; ++mf)
      #pragma unroll
      for (int r = 0; r < 4; ++r) {
        int xx = mf * 16 + ksub * 4 + r;
        float v = acc[mf][nf][r];
        eps[((e * 2 + ph) * 128 + 2 * xx + pw) * 17 + m15] = v;
        s1 += v; s2 += v * v;
      }
      s1 += __shfl_xor(s1, 16, 64); s1 += __shfl_xor(s1, 32, 64);
      s2 += __shfl_xor(s2, 16, 64); s2 += __shfl_xor(s2, 32, 64);
      if (lane < 16) {
        int co = nf * 16 + lane;
        size_t pidx = (((((size_t)b * 128 + co) * 128 + y0) * 2 + xh) * 4 + p) * 2;
        partial[pidx] = s1; partial[pidx + 1] = s2;
      }
    }
    __syncthreads();
    #pragma unroll
    for (int e = 0; e < 2; ++e) {
      int nf = r2 * 2 + e;
      int co = nf * 16 + co16;
      int h = 2 * y0 + ph2;
      float vv[16];
      #pragma unroll
      for (int i = 0; i < 16; ++i)
        vv[i] = eps[((e * 2 + ph2) * 128 + w16 * 16 + i) * 17 + co16];
      size_t obase = ((size_t)(b * 128 + co) * 256 + h) * 256 + xh * 128 + w16 * 16;
      if (BF16OUT) {
        u32x4 o0, o1;
        o0.x = (unsigned int)f2bf(vv[0])  | ((unsigned int)f2bf(vv[1])  << 16);
        o0.y = (unsigned int)f2bf(vv[2])  | ((unsigned int)f2bf(vv[3])  << 16);
        o0.z = (unsigned int)f2bf(vv[4])  | ((unsigned int)f2bf(vv[5])  << 16);
        o0.w = (unsigned int)f2bf(vv[6])  | ((unsigned int)f2bf(vv[7])  << 16);
        o1.x = (unsigned int)f2bf(vv[8])  | ((unsigned int)f2bf(vv[9])  << 16);
        o1.y = (unsigned int)f2bf(vv[10]) | ((unsigned int)f2bf(vv[11]) << 16);
        o1.z = (unsigned int)f2bf(vv[12]) | ((unsigned int)f2bf(vv[13]) << 16);
        o1.w = (unsigned int)f2bf(vv[14]) | ((unsigned int)f2bf(vv[15]) << 16);
        *(u32x4*)(xout + obase) = o0;
        *(u32x4*)(xout + obase + 8) = o1;
      } else {
        #pragma unroll
        for (int i = 0; i < 4; ++i) {
          f32x4 o4 = {vv[i * 4], vv[i * 4 + 1], vv[i * 4 + 2], vv[i * 4 + 3]};
          *(f32x4*)(out + obase + i * 4) = o4;
        }
      }
    }
    __syncthreads();
  }
}

// K4: reduce 2048 partials per (b,c) -> mean, rstd.
__global__ __launch_bounds__(256) void stats_kernel(const float* __restrict__ partial,
                                                    float* __restrict__ stats) {
  int bc = blockIdx.x;
  int t = threadIdx.x;
  float s1 = 0.f, s2 = 0.f;
  for (int j = t; j < 1024; j += 256) {
    s1 += partial[(size_t)bc * 2048 + 2 * j];
    s2 += partial[(size_t)bc * 2048 + 2 * j + 1];
  }
  #pragma unroll
  for (int m = 32; m; m >>= 1) { s1 += __shfl_xor(s1, m, 64); s2 += __shfl_xor(s2, m, 64); }
  __shared__ float rb[8];
  if ((t & 63) == 0) { rb[(t >> 6) * 2] = s1; rb[(t >> 6) * 2 + 1] = s2; }
  __syncthreads();
  if (t == 0) {
    float a1 = rb[0] + rb[2] + rb[4] + rb[6];
    float a2 = rb[1] + rb[3] + rb[5] + rb[7];
    float mean = a1 * (1.f / 65536.f);
    float var = a2 * (1.f / 65536.f) - mean * mean;
    stats[bc * 2] = mean;
    stats[bc * 2 + 1] = rsqrtf(var + 1e-5f);
  }
}

// K5a: normalize + modulate, fp32 in-place path.
__global__ __launch_bounds__(256) void final_kernel(float* __restrict__ out,
    const float* __restrict__ sw, const float* __restrict__ sb,
    const float* __restrict__ stats) {
  unsigned int tid = blockIdx.x * 256 + threadIdx.x;
  unsigned int e = tid * 4;
  unsigned int w = e & 255u;
  unsigned int h = (e >> 8) & 255u;
  unsigned int bc = e >> 16;
  float mean = stats[bc * 2], rstd = stats[bc * 2 + 1];
  unsigned int sidx = (bc * 32 + (h >> 3)) * 32 + (w >> 3);
  float f1 = (1.f + 0.3f * sw[sidx]) * rstd;
  float f0 = 0.3f * sb[sidx] - mean * f1;
  float4 v = *(float4*)(out + e);
  v.x = v.x * f1 + f0;
  v.y = v.y * f1 + f0;
  v.z = v.z * f1 + f0;
  v.w = v.w * f1 + f0;
  *(float4*)(out + e) = v;
}

// K5b: normalize + modulate, reading bf16 intermediate, writing fp32 out.
__global__ __launch_bounds__(256) void final_bf16_kernel(float* __restrict__ out,
    const unsigned short* __restrict__ xout,
    const float* __restrict__ sw, const float* __restrict__ sb,
    const float* __restrict__ stats) {
  unsigned int tid = blockIdx.x * 256 + threadIdx.x;
  unsigned int e = tid * 8;
  unsigned int w = e & 255u;
  unsigned int h = (e >> 8) & 255u;
  unsigned int bc = e >> 16;
  float mean = stats[bc * 2], rstd = stats[bc * 2 + 1];
  unsigned int sidx = (bc * 32 + (h >> 3)) * 32 + (w >> 3);
  float f1 = (1.f + 0.3f * sw[sidx]) * rstd;
  float f0 = 0.3f * sb[sidx] - mean * f1;
  u32x4 uv = *(const u32x4*)(xout + e);
  float o[8];
  #pragma unroll
  for (int j = 0; j < 4; ++j) {
    unsigned int word = uv[j];
    float lo = __builtin_bit_cast(float, word << 16);
    float hi = __builtin_bit_cast(float, word & 0xFFFF0000u);
    o[2 * j]     = lo * f1 + f0;
    o[2 * j + 1] = hi * f1 + f0;
  }
  f32x4 a = {o[0], o[1], o[2], o[3]}, c = {o[4], o[5], o[6], o[7]};
  *(f32x4*)(out + e) = a;
  *(f32x4*)(out + e + 4) = c;
}

extern "C" void kernel_launch(void* const* d_in, const int* in_sizes, int n_in,
                              void* d_out, int out_size, void* d_ws, size_t ws_size,
                              hipStream_t stream) {
  const float* x      = (const float*)d_in[0];
  const float* style  = (const float*)d_in[1];
  const float* weight = (const float*)d_in[2];
  const float* lin_w  = (const float*)d_in[3];
  const float* lin_b  = (const float*)d_in[4];
  const float* cw_w   = (const float*)d_in[5];
  const float* cw_b   = (const float*)d_in[6];
  const float* cb_w   = (const float*)d_in[7];
  const float* cb_b   = (const float*)d_in[8];
  float* out = (float*)d_out;
  char* ws = (char*)d_ws;

  short*          kbb   = (short*)(ws);                       // 1,179,648 B
  unsigned short* xt    = (unsigned short*)(ws + 1179648);    // 33,554,432 B
  float*          smap  = (float*)(ws + 34734080);            // 1 MB
  float*          swb   = (float*)(ws + 35782656);            // 4 MB
  float*          sbb   = (float*)(ws + 39976960);            // 4 MB
  float*          part  = (float*)(ws + 44171264);            // 8 MB
  float*          stats = (float*)(ws + 52559872);            // 8 KB
  unsigned short* xout  = (unsigned short*)(ws + 52568064);   // 128 MB (optional)
  bool bigws = ws_size >= (size_t)186785792;

  keffb_kernel<<<dim3(2304), dim3(256), 0, stream>>>(weight, kbb);
  xpose_kernel<<<dim3(128, 8), dim3(256), 0, stream>>>(x, xt);
  style_kernel<<<dim3(512), dim3(256), 0, stream>>>(style, lin_w, lin_b, smap);
  modconv_kernel<<<dim3(128, 8), dim3(256), 0, stream>>>(smap, cw_w, cw_b, cb_w, cb_b, swb, sbb);
  if (bigws) {
    main_kernel<1><<<dim3(2, 128, 8), dim3(256), 0, stream>>>(xt, kbb, out, xout, part);
    stats_kernel<<<dim3(1024), dim3(256), 0, stream>>>(part, stats);
    final_bf16_kernel<<<dim3(32768), dim3(256), 0, stream>>>(out, xout, swb, sbb, stats);
  } else {
    main_kernel<0><<<dim3(2, 128, 8), dim3(256), 0, stream>>>(xt, kbb, out, nullptr, part);
    stats_kernel<<<dim3(1024), dim3(256), 0, stream>>>(part, stats);
    final_kernel<<<dim3(65536), dim3(256), 0, stream>>>(out, swb, sbb, stats);
  }
}

// Round 5
// 343.807 us; speedup vs baseline: 1.8907x; 1.1452x over previous
//
#include <hip/hip_runtime.h>
#include <cstdint>

// B=8, Cin=Cout=128, x 128x128 -> out 256x256.
#define SCALE_MAIN 0.029462782549439483f   // 1/sqrt(128*9)
#define LSCALE     0.044194173824159223f   // 1/sqrt(512)
#define CSCALE     0.029462782549439483f   // 1/sqrt(128*9)

typedef __attribute__((ext_vector_type(8))) short bf16x8;
typedef __attribute__((ext_vector_type(4))) float f32x4;
typedef __attribute__((ext_vector_type(4))) unsigned int u32x4;

static __device__ __forceinline__ float lrelu_s2(float v) {
  return (v > 0.f ? v : 0.2f * v) * 1.4142135623730951f;
}

static __device__ __forceinline__ unsigned short f2bf(float f) {
  unsigned int u = __builtin_bit_cast(unsigned int, f);
  u += 0x7FFFu + ((u >> 16) & 1u);
  return (unsigned short)(u >> 16);
}

// K0: effective fused convT+blur kernel, bf16 in MFMA-B layout:
// kb[par][k/8][co][j], k = tap*128 + ci (tap = a*3+b2), j = ci&7.
__global__ __launch_bounds__(256) void keffb_kernel(const float* __restrict__ weight,
                                                    short* __restrict__ kb) {
  int idx = blockIdx.x * 256 + threadIdx.x;
  if (idx >= 128 * 128 * 36) return;
  int tap = idx % 9;
  int tmp = idx / 9;
  int par = tmp & 3;
  int cc  = tmp >> 2;            // co*128 + ci
  int co = cc >> 7, ci = cc & 127;
  int ph = par >> 1, pw = par & 1;
  int a = tap / 3, b = tap % 3;
  int th = ph ? 3 - 2 * a : 2 - 2 * a;
  int tw = pw ? 3 - 2 * b : 2 - 2 * b;
  const float k4[4] = {1.f, 3.f, 3.f, 1.f};
  const float* wp = weight + cc * 9;
  float acc = 0.f;
  #pragma unroll
  for (int u = 0; u < 4; ++u) {
    int m = th - 1 + u;
    if (m < 0 || m > 2) continue;
    #pragma unroll
    for (int v = 0; v < 4; ++v) {
      int n = tw - 1 + v;
      if (n < 0 || n > 2) continue;
      acc += (k4[3 - u] * k4[3 - v] * (1.f / 16.f)) * wp[m * 3 + n];
    }
  }
  kb[(((par * 144) + tap * 16 + (ci >> 3)) * 128 + co) * 8 + (ci & 7)] =
      (short)f2bf(acc * SCALE_MAIN);
}

// K0b: combined per-parity 2x2-tap modulation-conv weights, both convs stacked:
// kb2[((par*64 + k/8)*256 + co')*8 + k&7], k = t2*128+ci, t2 = dy2*2+dx2,
// co'<128 -> convw weights, co'>=128 -> convb. CSCALE folded in.
// S(p,d): taps of the 3-tap kernel contributing to sub-row d for parity p.
__global__ __launch_bounds__(256) void kb2_kernel(const float* __restrict__ cw_w,
                                                  const float* __restrict__ cb_w,
                                                  short* __restrict__ kb2) {
  int idx = blockIdx.x * 256 + threadIdx.x;
  if (idx >= 524288) return;
  int j   = idx & 7;
  int co  = (idx >> 3) & 255;
  int kc  = (idx >> 11) & 63;
  int par = idx >> 17;
  int k = kc * 8 + j;
  int t2 = k >> 7, ci = k & 127;
  int dy2 = t2 >> 1, dx2 = t2 & 1;
  int ph = par >> 1, pw = par & 1;
  const float* wsrc = (co < 128)
      ? cw_w + ((size_t)co * 128 + ci) * 9
      : cb_w + ((size_t)(co - 128) * 128 + ci) * 9;
  float acc = 0.f;
  #pragma unroll
  for (int kh = 0; kh < 3; ++kh) {
    bool okh = dy2 == 0 ? (ph == 0 ? kh == 0 : kh <= 1)
                        : (ph == 0 ? kh >= 1 : kh == 2);
    if (!okh) continue;
    #pragma unroll
    for (int kw = 0; kw < 3; ++kw) {
      bool okw = dx2 == 0 ? (pw == 0 ? kw == 0 : kw <= 1)
                          : (pw == 0 ? kw >= 1 : kw == 2);
      if (okw) acc += wsrc[kh * 3 + kw];
    }
  }
  kb2[idx] = (short)f2bf(acc * CSCALE);
}

// K_t: x NCHW fp32 -> NHWC bf16 via LDS-tiled transpose. Block = (y, b).
__global__ __launch_bounds__(256) void xpose_kernel(const float* __restrict__ x,
                                                    unsigned short* __restrict__ xt) {
  int y = blockIdx.x, b = blockIdx.y;
  __shared__ unsigned short tl[128 * 134];
  int t = threadIdx.x;
  #pragma unroll 4
  for (int i = 0; i < 16; ++i) {
    int c = t + i * 256;
    int ci = c >> 5, x4 = c & 31;
    f32x4 v = *(const f32x4*)(x + (size_t)(b * 128 + ci) * 16384 + y * 128 + x4 * 4);
    unsigned int* dst = (unsigned int*)(tl + ci * 134 + x4 * 4);
    dst[0] = (unsigned int)f2bf(v.x) | ((unsigned int)f2bf(v.y) << 16);
    dst[1] = (unsigned int)f2bf(v.z) | ((unsigned int)f2bf(v.w) << 16);
  }
  __syncthreads();
  #pragma unroll 2
  for (int i = 0; i < 8; ++i) {
    int c = t + i * 256;
    int xcol = c >> 4, sub = c & 15;
    unsigned short u[8];
    #pragma unroll
    for (int j = 0; j < 8; ++j) u[j] = tl[(sub * 8 + j) * 134 + xcol];
    u32x4 o;
    o.x = (unsigned int)u[0] | ((unsigned int)u[1] << 16);
    o.y = (unsigned int)u[2] | ((unsigned int)u[3] << 16);
    o.z = (unsigned int)u[4] | ((unsigned int)u[5] << 16);
    o.w = (unsigned int)u[6] | ((unsigned int)u[7] << 16);
    *(u32x4*)(xt + ((size_t)(b * 128 + y) * 128 + xcol) * 128 + sub * 8) = o;
  }
}

// K1: style GEMV + fused lrelu -> smap_bf[b][sp(16x16)][ci] bf16 (NHWC).
__global__ __launch_bounds__(256) void style_kernel(const float* __restrict__ style,
                                                    const float* __restrict__ lin_w,
                                                    const float* __restrict__ lin_b,
                                                    unsigned short* __restrict__ smap_bf) {
  int wid = threadIdx.x >> 6, lane = threadIdx.x & 63;
  int gw = blockIdx.x * 4 + wid;
  const float4* st4 = (const float4*)style;
  float s[8][8];
  #pragma unroll
  for (int b = 0; b < 8; ++b) {
    float4 a0 = st4[b * 128 + lane * 2];
    float4 a1 = st4[b * 128 + lane * 2 + 1];
    s[b][0] = a0.x; s[b][1] = a0.y; s[b][2] = a0.z; s[b][3] = a0.w;
    s[b][4] = a1.x; s[b][5] = a1.y; s[b][6] = a1.z; s[b][7] = a1.w;
  }
  for (int rr = 0; rr < 16; ++rr) {
    int j = gw * 16 + rr;
    const float4* wp = (const float4*)(lin_w + (size_t)j * 512);
    float4 w0 = wp[lane * 2], w1 = wp[lane * 2 + 1];
    float acc[8];
    #pragma unroll
    for (int b = 0; b < 8; ++b) {
      acc[b] = w0.x * s[b][0] + w0.y * s[b][1] + w0.z * s[b][2] + w0.w * s[b][3]
             + w1.x * s[b][4] + w1.y * s[b][5] + w1.z * s[b][6] + w1.w * s[b][7];
    }
    #pragma unroll
    for (int m = 32; m; m >>= 1) {
      #pragma unroll
      for (int b = 0; b < 8; ++b) acc[b] += __shfl_xor(acc[b], m, 64);
    }
    if (lane == 0) {
      float bias = lin_b[j];
      int ci = j >> 8, sp = j & 255;
      #pragma unroll
      for (int b = 0; b < 8; ++b)
        smap_bf[(size_t)(b * 256 + sp) * 128 + ci] =
            f2bf(lrelu_s2(acc[b] * LSCALE + bias));
    }
  }
}

// K2: modulation convs as MFMA implicit GEMM, parity-decomposed.
// Block (par, b), 8 waves: wave = (q = row-quad, ch = co-half).
// M = 256 px (16x16 s-grid), N = 256 (convw 0-127 | convb 128-255), K = 512.
// A staged in LDS [17x17 spatial][128 ci] bf16 with chunk swizzle (c+s)&15.
// Output: swp[b][co'][par][256 px] fp32 (+bias).
__global__ __launch_bounds__(512, 2) void modconv_kernel(
    const unsigned short* __restrict__ smap_bf, const short* __restrict__ kb2,
    const float* __restrict__ cw_b, const float* __restrict__ cb_b,
    float* __restrict__ swp) {
  extern __shared__ __align__(16) char dsm[];   // 73984 B
  int par = blockIdx.x, b = blockIdx.y;
  int ph = par >> 1, pw = par & 1;
  int t = threadIdx.x, lane = t & 63, w = t >> 6;
  int q = w >> 1, ch = w & 1;
  int m15 = lane & 15, ksub = lane >> 4;

  for (int c = t; c < 4624; c += 512) {
    int s = c >> 4, cch = c & 15;
    int rr = s / 17, cc = s - rr * 17;
    int gr = rr - 1 + ph, gc = cc - 1 + pw;
    u32x4 v = {0u, 0u, 0u, 0u};
    if ((unsigned)gr < 16u && (unsigned)gc < 16u)
      v = *(const u32x4*)(smap_bf + ((size_t)(b * 256 + gr * 16 + gc) * 128 + cch * 8));
    int phys = (cch + s) & 15;
    *(u32x4*)(dsm + s * 256 + phys * 16) = v;
  }
  __syncthreads();

  const bf16x8* kbv = (const bf16x8*)kb2;
  f32x4 acc[4][8];
  #pragma unroll
  for (int i = 0; i < 4; ++i)
  #pragma unroll
  for (int j = 0; j < 8; ++j) acc[i][j] = (f32x4){0.f, 0.f, 0.f, 0.f};

  for (int s = 0; s < 16; ++s) {
    int t2 = s >> 2, dy2 = t2 >> 1, dx2 = t2 & 1;
    int cch = (s & 3) * 4 + ksub;
    bf16x8 av[4];
    #pragma unroll
    for (int mf = 0; mf < 4; ++mf) {
      int i = q * 4 + mf;
      int ssp = (i + dy2) * 17 + (m15 + dx2);
      int phys = (cch + ssp) & 15;
      av[mf] = *(const bf16x8*)(dsm + ssp * 256 + phys * 16);
    }
    #pragma unroll
    for (int nf = 0; nf < 8; ++nf) {
      bf16x8 bv = kbv[(size_t)((par * 64 + s * 4 + ksub) * 256 + ch * 128 + nf * 16 + m15)];
      #pragma unroll
      for (int mf = 0; mf < 4; ++mf)
        acc[mf][nf] = __builtin_amdgcn_mfma_f32_16x16x32_bf16(av[mf], bv, acc[mf][nf], 0, 0, 0);
    }
  }

  int jbase = ksub * 4;
  #pragma unroll
  for (int nf = 0; nf < 8; ++nf) {
    int co = ch * 128 + nf * 16 + m15;
    float bias = (co < 128) ? cw_b[co] : cb_b[co - 128];
    #pragma unroll
    for (int mf = 0; mf < 4; ++mf) {
      int i = q * 4 + mf;
      #pragma unroll
      for (int r = 0; r < 4; ++r) {
        int px = i * 16 + jbase + r;
        swp[((size_t)(b * 256 + co) * 4 + par) * 256 + px] = acc[mf][nf][r] + bias;
      }
    }
  }
}

// K3: MFMA implicit-GEMM fused convT+blur (unchanged structure + setprio).
#define LOADSTEP(S, AV, BV)                                                      \
  {                                                                              \
    int tap_ = (S) >> 2;                                                         \
    int ta_ = (tap_ * 11) >> 5, tb_ = tap_ - ta_ * 3;                            \
    const char* ab_ = abase + (ta_ * 66 + tb_) * 272 + ((S) & 3) * 64;           \
    _Pragma("unroll")                                                            \
    for (int mf = 0; mf < 4; ++mf) AV[mf] = *(const bf16x8*)(ab_ + mf * 4352);   \
    _Pragma("unroll")                                                            \
    for (int nf = 0; nf < 8; ++nf) BV[nf] = kbv[bbase + (S) * 512 + nf * 16];    \
  }
#define MFMASTEP(AV, BV)                                                         \
  __builtin_amdgcn_s_setprio(1);                                                 \
  _Pragma("unroll")                                                              \
  for (int nf = 0; nf < 8; ++nf)                                                 \
  _Pragma("unroll")                                                              \
  for (int mf = 0; mf < 4; ++mf)                                                 \
    acc[mf][nf] = __builtin_amdgcn_mfma_f32_16x16x32_bf16(AV[mf], BV[nf], acc[mf][nf], 0, 0, 0); \
  __builtin_amdgcn_s_setprio(0);

template <int BF16OUT>
__global__ __launch_bounds__(256, 2) void main_kernel(const unsigned short* __restrict__ xt,
    const short* __restrict__ kb, float* __restrict__ out,
    unsigned short* __restrict__ xout, float* __restrict__ partial) {
  __shared__ __align__(16) char smem[53856];   // A-tile 198*272; reused as eps
  int xh = blockIdx.x, y0 = blockIdx.y, b = blockIdx.z;
  int x0 = xh * 64;
  int t = threadIdx.x;
  int lane = t & 63, p = t >> 6;               // p = parity 0..3
  int m15 = lane & 15, ksub = lane >> 4;
  int ph = p >> 1, pw = p & 1;

  // ---- stage A tile: 198 spatial x 128 ci bf16 ----
  const char* xtc = (const char*)xt;
  for (int c = t; c < 3168; c += 256) {
    int spos = c >> 4, sub = c & 15;
    int aa = spos / 66, cc2 = spos - aa * 66;
    int y = y0 - 1 + aa, xg = x0 - 1 + cc2;
    f32x4 v = {0.f, 0.f, 0.f, 0.f};
    if ((unsigned)y < 128u && (unsigned)xg < 128u)
      v = *(const f32x4*)(xtc + ((size_t)((b * 128 + y) * 128 + xg)) * 256 + sub * 16);
    *(f32x4*)(smem + spos * 272 + sub * 16) = v;
  }
  __syncthreads();

  // ---- K loop: 36 steps (9 taps x 4 ci-chunks of 32), pipelined ----
  const bf16x8* kbv = (const bf16x8*)kb;
  int bbase = p * 18432 + ksub * 128 + m15;
  const char* abase = smem + m15 * 272 + ksub * 16;

  f32x4 acc[4][8];
  #pragma unroll
  for (int i = 0; i < 4; ++i)
  #pragma unroll
  for (int j = 0; j < 8; ++j) acc[i][j] = (f32x4){0.f, 0.f, 0.f, 0.f};

  bf16x8 avA[4], bvA[8], avB[4], bvB[8];
  LOADSTEP(0, avA, bvA)
  for (int s = 0; s < 36; s += 2) {
    LOADSTEP(s + 1, avB, bvB)
    MFMASTEP(avA, bvA)
    if (s + 2 < 36) LOADSTEP(s + 2, avA, bvA)
    MFMASTEP(avB, bvB)
  }

  __syncthreads();                   // all waves done with A-tile
  // ---- epilogue: 4 rounds of 2 nf; eps [e2][ph2][w128][17] ----
  float* eps = (float*)smem;
  int co16 = t & 15, slotid = t >> 4;
  int ph2 = slotid >> 3, w16 = slotid & 7;
  #pragma unroll
  for (int r2 = 0; r2 < 4; ++r2) {
    #pragma unroll
    for (int e = 0; e < 2; ++e) {
      int nf = r2 * 2 + e;
      float s1 = 0.f, s2 = 0.f;
      #pragma unroll
      for (int mf = 0; mf < 4; ++mf)
      #pragma unroll
      for (int r = 0; r < 4; ++r) {
        int xx = mf * 16 + ksub * 4 + r;
        float v = acc[mf][nf][r];
        eps[((e * 2 + ph) * 128 + 2 * xx + pw) * 17 + m15] = v;
        s1 += v; s2 += v * v;
      }
      s1 += __shfl_xor(s1, 16, 64); s1 += __shfl_xor(s1, 32, 64);
      s2 += __shfl_xor(s2, 16, 64); s2 += __shfl_xor(s2, 32, 64);
      if (lane < 16) {
        int co = nf * 16 + lane;
        size_t pidx = (((((size_t)b * 128 + co) * 128 + y0) * 2 + xh) * 4 + p) * 2;
        partial[pidx] = s1; partial[pidx + 1] = s2;
      }
    }
    __syncthreads();
    #pragma unroll
    for (int e = 0; e < 2; ++e) {
      int nf = r2 * 2 + e;
      int co = nf * 16 + co16;
      int h = 2 * y0 + ph2;
      float vv[16];
      #pragma unroll
      for (int i = 0; i < 16; ++i)
        vv[i] = eps[((e * 2 + ph2) * 128 + w16 * 16 + i) * 17 + co16];
      size_t obase = ((size_t)(b * 128 + co) * 256 + h) * 256 + xh * 128 + w16 * 16;
      if (BF16OUT) {
        u32x4 o0, o1;
        o0.x = (unsigned int)f2bf(vv[0])  | ((unsigned int)f2bf(vv[1])  << 16);
        o0.y = (unsigned int)f2bf(vv[2])  | ((unsigned int)f2bf(vv[3])  << 16);
        o0.z = (unsigned int)f2bf(vv[4])  | ((unsigned int)f2bf(vv[5])  << 16);
        o0.w = (unsigned int)f2bf(vv[6])  | ((unsigned int)f2bf(vv[7])  << 16);
        o1.x = (unsigned int)f2bf(vv[8])  | ((unsigned int)f2bf(vv[9])  << 16);
        o1.y = (unsigned int)f2bf(vv[10]) | ((unsigned int)f2bf(vv[11]) << 16);
        o1.z = (unsigned int)f2bf(vv[12]) | ((unsigned int)f2bf(vv[13]) << 16);
        o1.w = (unsigned int)f2bf(vv[14]) | ((unsigned int)f2bf(vv[15]) << 16);
        *(u32x4*)(xout + obase) = o0;
        *(u32x4*)(xout + obase + 8) = o1;
      } else {
        #pragma unroll
        for (int i = 0; i < 4; ++i) {
          f32x4 o4 = {vv[i * 4], vv[i * 4 + 1], vv[i * 4 + 2], vv[i * 4 + 3]};
          *(f32x4*)(out + obase + i * 4) = o4;
        }
      }
    }
    __syncthreads();
  }
}

// K4: reduce 2048 partials per (b,c) -> mean, rstd.
__global__ __launch_bounds__(256) void stats_kernel(const float* __restrict__ partial,
                                                    float* __restrict__ stats) {
  int bc = blockIdx.x;
  int t = threadIdx.x;
  float s1 = 0.f, s2 = 0.f;
  for (int j = t; j < 1024; j += 256) {
    s1 += partial[(size_t)bc * 2048 + 2 * j];
    s2 += partial[(size_t)bc * 2048 + 2 * j + 1];
  }
  #pragma unroll
  for (int m = 32; m; m >>= 1) { s1 += __shfl_xor(s1, m, 64); s2 += __shfl_xor(s2, m, 64); }
  __shared__ float rb[8];
  if ((t & 63) == 0) { rb[(t >> 6) * 2] = s1; rb[(t >> 6) * 2 + 1] = s2; }
  __syncthreads();
  if (t == 0) {
    float a1 = rb[0] + rb[2] + rb[4] + rb[6];
    float a2 = rb[1] + rb[3] + rb[5] + rb[7];
    float mean = a1 * (1.f / 65536.f);
    float var = a2 * (1.f / 65536.f) - mean * mean;
    stats[bc * 2] = mean;
    stats[bc * 2 + 1] = rsqrtf(var + 1e-5f);
  }
}

// K5a: normalize + modulate, fp32 in-place path (parity swp layout).
__global__ __launch_bounds__(256) void final_kernel(float* __restrict__ out,
    const float* __restrict__ swp, const float* __restrict__ stats) {
  unsigned int tid = blockIdx.x * 256 + threadIdx.x;
  unsigned int e = tid * 4;
  unsigned int w = e & 255u;
  unsigned int h = (e >> 8) & 255u;
  unsigned int bc = e >> 16;
  unsigned int b = bc >> 7, co = bc & 127u;
  float mean = stats[bc * 2], rstd = stats[bc * 2 + 1];
  unsigned int r32 = h >> 3, c32 = w >> 3;
  unsigned int par = (r32 & 1u) * 2 + (c32 & 1u);
  unsigned int px = (r32 >> 1) * 16 + (c32 >> 1);
  float msw = swp[((size_t)(b * 256 + co) * 4 + par) * 256 + px];
  float msb = swp[((size_t)(b * 256 + 128 + co) * 4 + par) * 256 + px];
  float f1 = (1.f + 0.3f * msw) * rstd;
  float f0 = 0.3f * msb - mean * f1;
  float4 v = *(float4*)(out + e);
  v.x = v.x * f1 + f0;
  v.y = v.y * f1 + f0;
  v.z = v.z * f1 + f0;
  v.w = v.w * f1 + f0;
  *(float4*)(out + e) = v;
}

// K5b: normalize + modulate, reading bf16 intermediate, writing fp32 out.
__global__ __launch_bounds__(256) void final_bf16_kernel(float* __restrict__ out,
    const unsigned short* __restrict__ xout,
    const float* __restrict__ swp, const float* __restrict__ stats) {
  unsigned int tid = blockIdx.x * 256 + threadIdx.x;
  unsigned int e = tid * 8;
  unsigned int w = e & 255u;
  unsigned int h = (e >> 8) & 255u;
  unsigned int bc = e >> 16;
  unsigned int b = bc >> 7, co = bc & 127u;
  float mean = stats[bc * 2], rstd = stats[bc * 2 + 1];
  unsigned int r32 = h >> 3, c32 = w >> 3;
  unsigned int par = (r32 & 1u) * 2 + (c32 & 1u);
  unsigned int px = (r32 >> 1) * 16 + (c32 >> 1);
  float msw = swp[((size_t)(b * 256 + co) * 4 + par) * 256 + px];
  float msb = swp[((size_t)(b * 256 + 128 + co) * 4 + par) * 256 + px];
  float f1 = (1.f + 0.3f * msw) * rstd;
  float f0 = 0.3f * msb - mean * f1;
  u32x4 uv = *(const u32x4*)(xout + e);
  float o[8];
  #pragma unroll
  for (int j = 0; j < 4; ++j) {
    unsigned int word = uv[j];
    float lo = __builtin_bit_cast(float, word << 16);
    float hi = __builtin_bit_cast(float, word & 0xFFFF0000u);
    o[2 * j]     = lo * f1 + f0;
    o[2 * j + 1] = hi * f1 + f0;
  }
  f32x4 a = {o[0], o[1], o[2], o[3]}, c = {o[4], o[5], o[6], o[7]};
  *(f32x4*)(out + e) = a;
  *(f32x4*)(out + e + 4) = c;
}

extern "C" void kernel_launch(void* const* d_in, const int* in_sizes, int n_in,
                              void* d_out, int out_size, void* d_ws, size_t ws_size,
                              hipStream_t stream) {
  const float* x      = (const float*)d_in[0];
  const float* style  = (const float*)d_in[1];
  const float* weight = (const float*)d_in[2];
  const float* lin_w  = (const float*)d_in[3];
  const float* lin_b  = (const float*)d_in[4];
  const float* cw_w   = (const float*)d_in[5];
  const float* cw_b   = (const float*)d_in[6];
  const float* cb_w   = (const float*)d_in[7];
  const float* cb_b   = (const float*)d_in[8];
  float* out = (float*)d_out;
  char* ws = (char*)d_ws;

  // Layout (kb2/smap_bf overlap the part region -- dead before main writes it):
  short*          kbb     = (short*)(ws);                       // 1,179,648 B
  unsigned short* xt      = (unsigned short*)(ws + 1179648);    // 33,554,432 B
  float*          swp     = (float*)(ws + 34734080);            // 8 MB
  float*          part    = (float*)(ws + 43122688);            // 8 MB
  short*          kb2     = (short*)(ws + 43122688);            //   1 MB (overlap)
  unsigned short* smap_bf = (unsigned short*)(ws + 44171264);   //   512 KB (overlap)
  float*          stats   = (float*)(ws + 51511296);            // 8 KB
  unsigned short* xout    = (unsigned short*)(ws + 51519488);   // 128 MB (optional)
  bool bigws = ws_size >= (size_t)186785792;

  keffb_kernel<<<dim3(2304), dim3(256), 0, stream>>>(weight, kbb);
  kb2_kernel<<<dim3(2048), dim3(256), 0, stream>>>(cw_w, cb_w, kb2);
  xpose_kernel<<<dim3(128, 8), dim3(256), 0, stream>>>(x, xt);
  style_kernel<<<dim3(512), dim3(256), 0, stream>>>(style, lin_w, lin_b, smap_bf);
  modconv_kernel<<<dim3(4, 8), dim3(512), 73984, stream>>>(smap_bf, kb2, cw_b, cb_b, swp);
  if (bigws) {
    main_kernel<1><<<dim3(2, 128, 8), dim3(256), 0, stream>>>(xt, kbb, out, xout, part);
    stats_kernel<<<dim3(1024), dim3(256), 0, stream>>>(part, stats);
    final_bf16_kernel<<<dim3(32768), dim3(256), 0, stream>>>(out, xout, swp, stats);
  } else {
    main_kernel<0><<<dim3(2, 128, 8), dim3(256), 0, stream>>>(xt, kbb, out, nullptr, part);
    stats_kernel<<<dim3(1024), dim3(256), 0, stream>>>(part, stats);
    final_kernel<<<dim3(65536), dim3(256), 0, stream>>>(out, swp, stats);
  }
}